// Round 14
// baseline (87.819 us; speedup 1.0000x reference)
//
#include <hip/hip_runtime.h>
#include <math.h>

// Problem shape (fixed by the reference): B=4, S=4, N=2048, D=2048
#define NB 4
#define NS 4
#define NN 2048
#define ND 2048
#define NTHREADS 512
#define KPB 4            // (b,n) pairs per block, DMA-pipelined
#define SQRT_D 45.254833995939045f   // sqrt(2048)

typedef float f32x4 __attribute__((ext_vector_type(4)));

// Async global->LDS DMA (R5-proven on this problem): NO destination register,
// so the allocator cannot sink/remat the prefetch (R10/R12/R13 lesson: every
// reg-dest prefetch variant was defeated). 64 lanes x 16B; LDS dest is
// wave-uniform base + lane*16, global src is per-lane (rule #21 both-linear).
typedef __attribute__((address_space(3))) void lds_void_t;
typedef const __attribute__((address_space(1))) void glb_void_t;
#define ASYNC_COPY16(g, l) \
    __builtin_amdgcn_global_load_lds((glb_void_t*)(g), (lds_void_t*)(l), 16, 0, 0)

// Counted drain of the wave's own DMAs. vmcnt(N) waits for (outstanding-N)
// OLDEST ops (m135): at iter start the 4 newest are the previous iter's NT
// stores, everything older (our 4 DMAs) completes. Literal-stringized N.
#define VMW_(N) do {                                           \
    asm volatile("s_waitcnt vmcnt(" #N ")" ::: "memory");      \
    __builtin_amdgcn_sched_barrier(0); } while (0)
#define VMW(N) VMW_(N)

// Compaction-butterfly ship, literal indices only (R3 lesson, R5/R7/R9-proven).
#define SHIP(I, H, M_) {                                      \
    const float keep_ = hi_ ? v[(I)+(H)] : v[(I)];            \
    const float give_ = hi_ ? v[(I)] : v[(I)+(H)];            \
    v[(I)] = keep_ + __shfl_xor(give_, (M_)); }

#define BUTTERFLY()                                                          \
    { const bool hi_ = (lane & 1) != 0;                                      \
      SHIP(0,16,1)  SHIP(1,16,1)  SHIP(2,16,1)  SHIP(3,16,1)                 \
      SHIP(4,16,1)  SHIP(5,16,1)  SHIP(6,16,1)  SHIP(7,16,1)                 \
      SHIP(8,16,1)  SHIP(9,16,1)  SHIP(10,16,1) SHIP(11,16,1)                \
      SHIP(12,16,1) SHIP(13,16,1) SHIP(14,16,1) SHIP(15,16,1) }              \
    { const bool hi_ = (lane & 2) != 0;                                      \
      SHIP(0,8,2) SHIP(1,8,2) SHIP(2,8,2) SHIP(3,8,2)                        \
      SHIP(4,8,2) SHIP(5,8,2) SHIP(6,8,2) SHIP(7,8,2) }                      \
    { const bool hi_ = (lane & 4) != 0;                                      \
      SHIP(0,4,4) SHIP(1,4,4) SHIP(2,4,4) SHIP(3,4,4) }                      \
    { const bool hi_ = (lane & 8) != 0;                                      \
      SHIP(0,2,8) SHIP(1,2,8) }                                              \
    { const bool hi_ = (lane & 16) != 0;                                     \
      SHIP(0,1,16) }

// One (b,n) iteration. BF = current LDS buffer (literal 0/1), K/PREF/WN
// literal at every expansion. Wave reads exactly the slice its own DMA
// staged -> per-wave vmcnt suffices, NO staging barrier anywhere.
// Double-buffer safety: xbuf[BF^1] was last read 2 barriers ago.
#define ITER(K, BF, PREF, WN)                                                \
  {                                                                          \
    VMW(WN);                                                                 \
    f32x4 x0 = *(const f32x4*)&xbuf[BF][0][d];   /* ds_read_b128, own slice */\
    f32x4 x1 = *(const f32x4*)&xbuf[BF][1][d];                               \
    f32x4 x2 = *(const f32x4*)&xbuf[BF][2][d];                               \
    f32x4 x3 = *(const f32x4*)&xbuf[BF][3][d];                               \
    float v[32];                                                             \
    _Pragma("unroll") for (int q = 0; q < 32; ++q) v[q] = 0.f;               \
    {                                                                        \
      f32x4 g4 = *(const f32x4*)(gamma + d);                                 \
      _Pragma("unroll") for (int e = 0; e < 4; ++e) {                        \
        v[0]  = __builtin_fmaf(x0[e], x0[e], v[0]);                          \
        v[7]  = __builtin_fmaf(x1[e], x1[e], v[7]);                          \
        v[14] = __builtin_fmaf(x2[e], x2[e], v[14]);                         \
        v[21] = __builtin_fmaf(x3[e], x3[e], v[21]);                         \
      }                                                                      \
      _Pragma("unroll") for (int j = 0; j < 6; ++j) {                        \
        const float* wsrc = (j < 5) ? (w_alpha + (size_t)j * ND + d)         \
                                    : (w_beta + d);                          \
        f32x4 w4 = *(const f32x4*)wsrc;                                      \
        f32x4 wg = w4 + w4 * g4;        /* w * (1 + gamma) */                \
        _Pragma("unroll") for (int e = 0; e < 4; ++e) {                      \
          v[1 + j]  = __builtin_fmaf(x0[e], wg[e], v[1 + j]);                \
          v[8 + j]  = __builtin_fmaf(x1[e], wg[e], v[8 + j]);                \
          v[15 + j] = __builtin_fmaf(x2[e], wg[e], v[15 + j]);               \
          v[22 + j] = __builtin_fmaf(x3[e], wg[e], v[22 + j]);               \
        }                                                                    \
      }                                                                      \
    }                                                                        \
    BUTTERFLY()                                                              \
    const float tot##K = v[0] + __shfl_xor(v[0], 32);                        \
    if (lane < 32) red[wave][bidx] = tot##K;                                 \
    __syncthreads();                                                         \
    if (tid < 24) {                                                          \
      float ssq_ = 0.f, dot_ = 0.f;                                          \
      _Pragma("unroll") for (int w = 0; w < 8; ++w) {                        \
        ssq_ += red[w][es * 7];                                              \
        dot_ += red[w][es * 7 + 1 + ej];                                     \
      }                                                                      \
      const float rs_ = SQRT_D / fmaxf(sqrtf(ssq_), 1e-12f);                 \
      asb[es][ej] = __builtin_fmaf(tanhf(dot_ * rs_),                        \
                                   (ej < 5) ? sa : sb, stat);                \
    }                                                                        \
    __syncthreads();                                                         \
    /* DMA bn K+1 FIRST (so NT stores below are the 4 newest VMEM ops);  */  \
    /* no barrier between issue and next iter's counted wait.            */  \
    if (PREF) {                                                              \
      const float* np_ = xp + ((K) + 1) * ND;                                \
      ASYNC_COPY16(np_,                  &xbuf[(BF) ^ 1][0][wave << 8]);     \
      ASYNC_COPY16(np_ + row_stride,     &xbuf[(BF) ^ 1][1][wave << 8]);     \
      ASYNC_COPY16(np_ + 2 * row_stride, &xbuf[(BF) ^ 1][2][wave << 8]);     \
      ASYNC_COPY16(np_ + 3 * row_stride, &xbuf[(BF) ^ 1][3][wave << 8]);     \
      __builtin_amdgcn_sched_barrier(0);  /* stores must stay below */       \
    }                                                                        \
    {                                                                        \
      float M[NS][NS];                                                       \
      _Pragma("unroll") for (int so = 0; so < NS; ++so)                      \
        _Pragma("unroll") for (int si = 0; si < NS; ++si)                    \
          M[so][si] = __builtin_fmaf(asb[so][5], asb[si][0],                 \
                                     asb[si][so + 1]);                       \
      float* op_ = op + (K) * ND;                                            \
      _Pragma("unroll") for (int so = 0; so < NS; ++so) {                    \
        f32x4 o;                                                             \
        _Pragma("unroll") for (int e = 0; e < 4; ++e)                        \
          o[e] = M[so][0] * x0[e] + M[so][1] * x1[e]                         \
               + M[so][2] * x2[e] + M[so][3] * x3[e];                        \
        __builtin_nontemporal_store(o, (f32x4*)(op_ + (size_t)so * row_stride)); \
      }                                                                      \
    }                                                                        \
  }

// 512 threads, one f32x4 chunk per thread, 4 bn per block, LDS-DMA
// double-buffered prefetch. VGPR budget: x[16]+v[32]+temps ~= 90 < 128.
__global__ __launch_bounds__(NTHREADS, 4)
void hyperconn_kernel(const float* __restrict__ residuals,
                      const float* __restrict__ gamma,
                      const float* __restrict__ w_alpha,
                      const float* __restrict__ scale_alpha,
                      const float* __restrict__ static_alpha,
                      const float* __restrict__ w_beta,
                      const float* __restrict__ scale_beta,
                      const float* __restrict__ static_beta,
                      float* __restrict__ out)
{
    __shared__ float xbuf[2][NS][ND];  // 64 KB: double-buffered x tiles
    __shared__ float red[8][32];       // per-wave compacted sums (idx = brev5)
    __shared__ float asb[NS][6];       // [s][0..4]=alpha row, [s][5]=beta

    const int tid  = threadIdx.x;
    const int blk  = blockIdx.x;              // 0 .. 2047
    const int b    = blk >> 9;                // 512 blocks per b
    const int n0   = (blk & 511) * KPB;       // 4 adjacent n
    const int wave = tid >> 6;
    const int lane = tid & 63;
    const int d    = tid << 2;                // = wave*256 + lane*4

    const size_t row_stride = (size_t)NN * ND;
    const float* xp = residuals + (size_t)(b * NS) * row_stride + (size_t)n0 * ND + d;
    float*       op = out       + (size_t)(b * NS) * row_stride + (size_t)n0 * ND + d;

    // Hoisted epilogue constants: no compiler VMEM between DMA issue and the
    // NT stores inside the iter body (keeps the vmcnt(4) count exact).
    const float sa = scale_alpha[0], sb = scale_beta[0];
    const int t24 = (tid < 24) ? tid : 0;
    const int es = t24 / 6, ej = t24 % 6;
    const float stat = (ej < 5) ? static_alpha[es * 5 + ej] : static_beta[es];
    const int bidx = ((lane & 1) << 4) | ((lane & 2) << 2) | (lane & 4)
                   | ((lane & 8) >> 2) | ((lane & 16) >> 4);   // brev5(lane&31)

    // Prologue: DMA bn0 into buffer 0 (own slice; drained by ITER0's vmcnt(0))
    ASYNC_COPY16(xp,                  &xbuf[0][0][wave << 8]);
    ASYNC_COPY16(xp + row_stride,     &xbuf[0][1][wave << 8]);
    ASYNC_COPY16(xp + 2 * row_stride, &xbuf[0][2][wave << 8]);
    ASYNC_COPY16(xp + 3 * row_stride, &xbuf[0][3][wave << 8]);

    ITER(0, 0, 1, 0)
    ITER(1, 1, 1, 4)
    ITER(2, 0, 1, 4)
    ITER(3, 1, 0, 4)
}

extern "C" void kernel_launch(void* const* d_in, const int* in_sizes, int n_in,
                              void* d_out, int out_size, void* d_ws, size_t ws_size,
                              hipStream_t stream) {
    const float* residuals    = (const float*)d_in[0];
    const float* gamma        = (const float*)d_in[1];
    const float* w_alpha      = (const float*)d_in[2];
    const float* scale_alpha  = (const float*)d_in[3];
    const float* static_alpha = (const float*)d_in[4];
    const float* w_beta       = (const float*)d_in[5];
    const float* scale_beta   = (const float*)d_in[6];
    const float* static_beta  = (const float*)d_in[7];
    float* out = (float*)d_out;

    const int grid = NB * NN / KPB;  // 2048 blocks, 4 bn each
    hyperconn_kernel<<<grid, NTHREADS, 0, stream>>>(
        residuals, gamma, w_alpha, scale_alpha, static_alpha,
        w_beta, scale_beta, static_beta, out);
}